// Round 1
// baseline (432.029 us; speedup 1.0000x reference)
//
#include <hip/hip_runtime.h>

// out = joints @ R + t, R = RX(roll) @ RY(pitch) @ RZ(yaw), per reference.
// Streaming memory-bound op: 169 MB in + 169 MB out, roofline ~54 us @ 6.3 TB/s.
//
// v2 changes vs the 287us baseline:
//  - __sinf/__cosf (native v_sin_f32/v_cos_f32) instead of libm sincosf:
//    removes ~180 VALU instr/thread incl. Payne-Hanek branch code. R is
//    wave-uniform; with 165K waves the libm path was ~35-40us of VALU,
//    co-limiting with memory.
//  - 8 points/thread (24 floats = 6 float4): halves wave count, doubles
//    loads-in-flight per wave, amortizes the uniform R computation.
//  - nontemporal stores: output is never re-read; skip write-allocate
//    pollution of L2/LLC against the read stream.
//  - loads stay cached: each 128B line is touched by multiple float4 loads
//    (48B/thread stride), needs L1/L2 line reuse.

using f4 = __attribute__((ext_vector_type(4))) float;

__global__ __launch_bounds__(256) void Transform_38723425141290_kernel(
    const float* __restrict__ joints,
    const float* __restrict__ orient,
    const float* __restrict__ trans,
    float* __restrict__ out,
    long long n_groups,   // number of 8-point (24-float) groups
    long long n_points)   // total point count
{
    // --- rotation matrix (wave-uniform; tiny cached reads) ---
    const float roll = orient[0], pitch = orient[1], yaw = orient[2];
    const float sr = __sinf(roll),  cr = __cosf(roll);
    const float sp = __sinf(pitch), cp = __cosf(pitch);
    const float sy = __sinf(yaw),   cy = __cosf(yaw);

    const float R00 = cp * cy;
    const float R01 = -cp * sy;
    const float R02 = sp;
    const float R10 = sr * sp * cy + cr * sy;
    const float R11 = cr * cy - sr * sp * sy;
    const float R12 = -sr * cp;
    const float R20 = sr * sy - cr * sp * cy;
    const float R21 = cr * sp * sy + sr * cy;
    const float R22 = cr * cp;

    const float tx = trans[0], ty = trans[1], tz = trans[2];

    const long long g = (long long)blockIdx.x * blockDim.x + threadIdx.x;

    if (g < n_groups) {
        const f4* jp = reinterpret_cast<const f4*>(joints) + g * 6;
        f4 a = jp[0], b = jp[1], c = jp[2], d = jp[3], e = jp[4], f = jp[5];

        f4 o0, o1, o2, o3, o4, o5;
        // (x,y,z) -> (ox,oy,oz)
        #define ROT(x, y, z, ox, oy, oz)              \
            ox = x * R00 + y * R10 + z * R20 + tx;    \
            oy = x * R01 + y * R11 + z * R21 + ty;    \
            oz = x * R02 + y * R12 + z * R22 + tz;

        // 8 points unpacked from 24 consecutive floats
        ROT(a.x, a.y, a.z, o0.x, o0.y, o0.z)
        ROT(a.w, b.x, b.y, o0.w, o1.x, o1.y)
        ROT(b.z, b.w, c.x, o1.z, o1.w, o2.x)
        ROT(c.y, c.z, c.w, o2.y, o2.z, o2.w)
        ROT(d.x, d.y, d.z, o3.x, o3.y, o3.z)
        ROT(d.w, e.x, e.y, o3.w, o4.x, o4.y)
        ROT(e.z, e.w, f.x, o4.z, o4.w, o5.x)
        ROT(f.y, f.z, f.w, o5.y, o5.z, o5.w)
        #undef ROT

        f4* op = reinterpret_cast<f4*>(out) + g * 6;
        __builtin_nontemporal_store(o0, op + 0);
        __builtin_nontemporal_store(o1, op + 1);
        __builtin_nontemporal_store(o2, op + 2);
        __builtin_nontemporal_store(o3, op + 3);
        __builtin_nontemporal_store(o4, op + 4);
        __builtin_nontemporal_store(o5, op + 5);
    }

    // scalar tail (n_points % 8 != 0) — dead for this shape, kept for safety
    const long long tail_base = n_groups * 8;
    if (g < (n_points - tail_base)) {
        const long long i = tail_base + g;
        const float x = joints[i * 3 + 0];
        const float y = joints[i * 3 + 1];
        const float z = joints[i * 3 + 2];
        out[i * 3 + 0] = x * R00 + y * R10 + z * R20 + tx;
        out[i * 3 + 1] = x * R01 + y * R11 + z * R21 + ty;
        out[i * 3 + 2] = x * R02 + y * R12 + z * R22 + tz;
    }
}

extern "C" void kernel_launch(void* const* d_in, const int* in_sizes, int n_in,
                              void* d_out, int out_size, void* d_ws, size_t ws_size,
                              hipStream_t stream) {
    const float* joints = (const float*)d_in[0];
    const float* orient = (const float*)d_in[1];
    const float* trans  = (const float*)d_in[2];
    float* out = (float*)d_out;

    const long long n_floats = (long long)in_sizes[0];
    const long long n_points = n_floats / 3;
    const long long n_groups = n_points / 8;

    const int block = 256;
    long long work = n_groups > 0 ? n_groups : 1;
    const long long grid = (work + block - 1) / block;

    Transform_38723425141290_kernel<<<dim3((unsigned)grid), dim3(block), 0, stream>>>(
        joints, orient, trans, out, n_groups, n_points);
}

// Round 2
// 297.622 us; speedup vs baseline: 1.4516x; 1.4516x over previous
//
#include <hip/hip_runtime.h>

// out = joints @ R + t, R = RX(roll) @ RY(pitch) @ RZ(yaw), per reference.
// Streaming memory-bound op: 169 MB in + 169 MB out, roofline ~54 us @ 6.3 TB/s.
//
// v3 changes vs v2 (245us kernel dispatch, dur_us 432):
//  - REVERT nontemporal stores -> regular stores. rocprof showed
//    WRITE_SIZE 399 MB vs 169 MB ideal (2.3x write amplification): with
//    96B lane stride no single store instruction covers a full 64B sector,
//    and nt (no-allocate) defeated the L2 write-merging that makes the
//    partial-line pattern free. Regular write-back L2 merges the 6 stores
//    per thread into fully-dirty lines.
//  - KEEP __sinf/__cosf (VALUBusy was 2.3% -- trig cost is gone).
//  - KEEP 8 points/thread (6 float4 loads + 6 float4 stores in flight).

using f4 = __attribute__((ext_vector_type(4))) float;

__global__ __launch_bounds__(256) void Transform_38723425141290_kernel(
    const float* __restrict__ joints,
    const float* __restrict__ orient,
    const float* __restrict__ trans,
    float* __restrict__ out,
    long long n_groups,   // number of 8-point (24-float) groups
    long long n_points)   // total point count
{
    // --- rotation matrix (wave-uniform; tiny cached reads) ---
    const float roll = orient[0], pitch = orient[1], yaw = orient[2];
    const float sr = __sinf(roll),  cr = __cosf(roll);
    const float sp = __sinf(pitch), cp = __cosf(pitch);
    const float sy = __sinf(yaw),   cy = __cosf(yaw);

    const float R00 = cp * cy;
    const float R01 = -cp * sy;
    const float R02 = sp;
    const float R10 = sr * sp * cy + cr * sy;
    const float R11 = cr * cy - sr * sp * sy;
    const float R12 = -sr * cp;
    const float R20 = sr * sy - cr * sp * cy;
    const float R21 = cr * sp * sy + sr * cy;
    const float R22 = cr * cp;

    const float tx = trans[0], ty = trans[1], tz = trans[2];

    const long long g = (long long)blockIdx.x * blockDim.x + threadIdx.x;

    if (g < n_groups) {
        const f4* jp = reinterpret_cast<const f4*>(joints) + g * 6;
        f4 a = jp[0], b = jp[1], c = jp[2], d = jp[3], e = jp[4], f = jp[5];

        f4 o0, o1, o2, o3, o4, o5;
        // (x,y,z) -> (ox,oy,oz)
        #define ROT(x, y, z, ox, oy, oz)              \
            ox = x * R00 + y * R10 + z * R20 + tx;    \
            oy = x * R01 + y * R11 + z * R21 + ty;    \
            oz = x * R02 + y * R12 + z * R22 + tz;

        // 8 points unpacked from 24 consecutive floats
        ROT(a.x, a.y, a.z, o0.x, o0.y, o0.z)
        ROT(a.w, b.x, b.y, o0.w, o1.x, o1.y)
        ROT(b.z, b.w, c.x, o1.z, o1.w, o2.x)
        ROT(c.y, c.z, c.w, o2.y, o2.z, o2.w)
        ROT(d.x, d.y, d.z, o3.x, o3.y, o3.z)
        ROT(d.w, e.x, e.y, o3.w, o4.x, o4.y)
        ROT(e.z, e.w, f.x, o4.z, o4.w, o5.x)
        ROT(f.y, f.z, f.w, o5.y, o5.z, o5.w)
        #undef ROT

        f4* op = reinterpret_cast<f4*>(out) + g * 6;
        op[0] = o0;
        op[1] = o1;
        op[2] = o2;
        op[3] = o3;
        op[4] = o4;
        op[5] = o5;
    }

    // scalar tail (n_points % 8 != 0) — dead for this shape, kept for safety
    const long long tail_base = n_groups * 8;
    if (g < (n_points - tail_base)) {
        const long long i = tail_base + g;
        const float x = joints[i * 3 + 0];
        const float y = joints[i * 3 + 1];
        const float z = joints[i * 3 + 2];
        out[i * 3 + 0] = x * R00 + y * R10 + z * R20 + tx;
        out[i * 3 + 1] = x * R01 + y * R11 + z * R21 + ty;
        out[i * 3 + 2] = x * R02 + y * R12 + z * R22 + tz;
    }
}

extern "C" void kernel_launch(void* const* d_in, const int* in_sizes, int n_in,
                              void* d_out, int out_size, void* d_ws, size_t ws_size,
                              hipStream_t stream) {
    const float* joints = (const float*)d_in[0];
    const float* orient = (const float*)d_in[1];
    const float* trans  = (const float*)d_in[2];
    float* out = (float*)d_out;

    const long long n_floats = (long long)in_sizes[0];
    const long long n_points = n_floats / 3;
    const long long n_groups = n_points / 8;

    const int block = 256;
    long long work = n_groups > 0 ? n_groups : 1;
    const long long grid = (work + block - 1) / block;

    Transform_38723425141290_kernel<<<dim3((unsigned)grid), dim3(block), 0, stream>>>(
        joints, orient, trans, out, n_groups, n_points);
}

// Round 3
// 289.279 us; speedup vs baseline: 1.4935x; 1.0288x over previous
//
#include <hip/hip_runtime.h>

// out = joints @ R + t, R = RX(roll) @ RY(pitch) @ RZ(yaw), per reference.
// Streaming memory-bound op: 169 MB in + 169 MB out, roofline ~54 us @ 6.3 TB/s.
//
// v4 changes vs v3 (kernel dispatch 102 us, ~3.3 TB/s combined, VALUBusy 2%):
//  - Diagnosis: not HBM-bound, not VALU-bound -> vector-memory REQUEST-rate
//    bound. 24 floats/thread means every float4 load/store has a 96 B
//    inter-lane stride: 64 lanes hit ~64 distinct cache lines per
//    instruction (vs 16 dense) -> ~4x TA/TCP request amplification on both
//    streams. Bytes were fine (WRITE_SIZE was exactly ideal); requests were
//    the ceiling.
//  - Fix: block-cooperative LDS transpose. Each block stages a 24 KB
//    contiguous region with DENSE float4 loads (lane stride 16 B, full-line
//    coverage per instruction), threads read their 8 points from LDS,
//    write results to LDS, block stores the region back densely.
//  - LDS XOR swizzle i ^ ((i>>3)&7) on every LDS access: breaks the 4-way
//    bank conflict of the 96B-stride fragment reads; keeps the linear
//    staging phases at the free 2-way level. 24 KB/block -> 6 blocks/CU.
//  - KEEP __sinf/__cosf, regular (write-back) stores.

using f4 = __attribute__((ext_vector_type(4))) float;

#define BLOCK 256
#define F4_PER_THREAD 6
#define F4_PER_BLOCK (BLOCK * F4_PER_THREAD)      // 1536 float4 = 24 KB
#define PTS_PER_BLOCK ((F4_PER_BLOCK * 4) / 3)    // 2048 points (exact)

__device__ __forceinline__ int swz(int i) { return i ^ ((i >> 3) & 7); }

__global__ __launch_bounds__(BLOCK) void Transform_38723425141290_kernel(
    const float* __restrict__ joints,
    const float* __restrict__ orient,
    const float* __restrict__ trans,
    float* __restrict__ out,
    long long n_points)
{
    __shared__ f4 lds[F4_PER_BLOCK];

    // --- rotation matrix (wave-uniform; tiny cached reads) ---
    const float roll = orient[0], pitch = orient[1], yaw = orient[2];
    const float sr = __sinf(roll),  cr = __cosf(roll);
    const float sp = __sinf(pitch), cp = __cosf(pitch);
    const float sy = __sinf(yaw),   cy = __cosf(yaw);

    const float R00 = cp * cy;
    const float R01 = -cp * sy;
    const float R02 = sp;
    const float R10 = sr * sp * cy + cr * sy;
    const float R11 = cr * cy - sr * sp * sy;
    const float R12 = -sr * cp;
    const float R20 = sr * sy - cr * sp * cy;
    const float R21 = cr * sp * sy + sr * cy;
    const float R22 = cr * cp;

    const float tx = trans[0], ty = trans[1], tz = trans[2];

    const int tid = threadIdx.x;
    const long long blk = blockIdx.x;

    if ((blk + 1) * (long long)PTS_PER_BLOCK <= n_points) {
        // ---- fast path: full 2048-point region, fully coalesced ----
        const long long f4_base = blk * (long long)F4_PER_BLOCK;
        const f4* jp = reinterpret_cast<const f4*>(joints) + f4_base;

        #pragma unroll
        for (int k = 0; k < F4_PER_THREAD; ++k)
            lds[swz(k * BLOCK + tid)] = jp[k * BLOCK + tid];
        __syncthreads();

        // each thread owns 6 consecutive float4s = 24 floats = 8 points
        f4 a = lds[swz(tid * 6 + 0)];
        f4 b = lds[swz(tid * 6 + 1)];
        f4 c = lds[swz(tid * 6 + 2)];
        f4 d = lds[swz(tid * 6 + 3)];
        f4 e = lds[swz(tid * 6 + 4)];
        f4 f = lds[swz(tid * 6 + 5)];

        f4 o0, o1, o2, o3, o4, o5;
        #define ROT(x, y, z, ox, oy, oz)              \
            ox = x * R00 + y * R10 + z * R20 + tx;    \
            oy = x * R01 + y * R11 + z * R21 + ty;    \
            oz = x * R02 + y * R12 + z * R22 + tz;

        ROT(a.x, a.y, a.z, o0.x, o0.y, o0.z)
        ROT(a.w, b.x, b.y, o0.w, o1.x, o1.y)
        ROT(b.z, b.w, c.x, o1.z, o1.w, o2.x)
        ROT(c.y, c.z, c.w, o2.y, o2.z, o2.w)
        ROT(d.x, d.y, d.z, o3.x, o3.y, o3.z)
        ROT(d.w, e.x, e.y, o3.w, o4.x, o4.y)
        ROT(e.z, e.w, f.x, o4.z, o4.w, o5.x)
        ROT(f.y, f.z, f.w, o5.y, o5.z, o5.w)
        #undef ROT

        // thread-private slots: no barrier needed between read and write
        lds[swz(tid * 6 + 0)] = o0;
        lds[swz(tid * 6 + 1)] = o1;
        lds[swz(tid * 6 + 2)] = o2;
        lds[swz(tid * 6 + 3)] = o3;
        lds[swz(tid * 6 + 4)] = o4;
        lds[swz(tid * 6 + 5)] = o5;
        __syncthreads();

        f4* op = reinterpret_cast<f4*>(out) + f4_base;
        #pragma unroll
        for (int k = 0; k < F4_PER_THREAD; ++k)
            op[k * BLOCK + tid] = lds[swz(k * BLOCK + tid)];
    } else {
        // ---- tail block: scalar per-point (dead for this shape) ----
        for (long long p = blk * (long long)PTS_PER_BLOCK + tid; p < n_points;
             p += BLOCK) {
            const float x = joints[p * 3 + 0];
            const float y = joints[p * 3 + 1];
            const float z = joints[p * 3 + 2];
            out[p * 3 + 0] = x * R00 + y * R10 + z * R20 + tx;
            out[p * 3 + 1] = x * R01 + y * R11 + z * R21 + ty;
            out[p * 3 + 2] = x * R02 + y * R12 + z * R22 + tz;
        }
    }
}

extern "C" void kernel_launch(void* const* d_in, const int* in_sizes, int n_in,
                              void* d_out, int out_size, void* d_ws, size_t ws_size,
                              hipStream_t stream) {
    const float* joints = (const float*)d_in[0];
    const float* orient = (const float*)d_in[1];
    const float* trans  = (const float*)d_in[2];
    float* out = (float*)d_out;

    const long long n_floats = (long long)in_sizes[0];
    const long long n_points = n_floats / 3;

    const long long grid =
        (n_points + PTS_PER_BLOCK - 1) / PTS_PER_BLOCK;

    Transform_38723425141290_kernel<<<dim3((unsigned)grid), dim3(BLOCK), 0, stream>>>(
        joints, orient, trans, out, n_points);
}